// Round 5
// baseline (152.326 us; speedup 1.0000x reference)
//
#include <hip/hip_runtime.h>

#define Bq 8
#define Sq 1024
#define Dq 512

typedef __attribute__((ext_vector_type(8))) short bf16x8;
typedef __attribute__((ext_vector_type(4))) float f32x4;

__device__ __forceinline__ unsigned short f2bf(float f) {
  unsigned int u = __float_as_uint(f);
  return (unsigned short)((u + 0x7fffu + ((u >> 16) & 1u)) >> 16);
}

__device__ __forceinline__ void load_lds16(const unsigned short* g, unsigned short* l) {
  __builtin_amdgcn_global_load_lds(
      (const __attribute__((address_space(1))) unsigned int*)g,
      (__attribute__((address_space(3))) unsigned int*)l, 16, 0, 0);
}

// Permuted+swizzled B layout ("k-chunk-major"): element B[n][k] lives at
//   kc*16384 + n*32 + ((ksg ^ ((n>>1)&3))*8) + k7
// kc = k>>5, ksg = (k>>3)&3, k7 = k&7. Chunk = the 32KB LDS staging image.

// ================= dispatch 1: prep_t — inp transpose + colsum only =========
// 1024 blocks: b = idx&7 (XCD-pinned), tt = (idx>>3)&15 (64-row t-stripe),
// dd = idx>>7 (64-col d-stripe). float4 loads, ushort4 transposed stores.
__global__ __launch_bounds__(256) void prep_t(
    const float* __restrict__ inp,
    unsigned short* __restrict__ inpT, float* __restrict__ partial) {
  __shared__ unsigned short tile[64][66];
  __shared__ float csum[16][64];
  int idx = blockIdx.x;
  int tid = threadIdx.x;
  int b = idx & 7, tt = (idx >> 3) & 15, dd = idx >> 7;
  int r = tid >> 4, c4 = (tid & 15) * 4;
  const float* src = inp + ((size_t)b * Sq + tt * 64) * Dq + dd * 64;
  float cp0 = 0.f, cp1 = 0.f, cp2 = 0.f, cp3 = 0.f;
#pragma unroll
  for (int p = 0; p < 4; ++p) {
    float4 v = *(const float4*)(src + (size_t)(r + p * 16) * Dq + c4);
    ushort4 o; o.x = f2bf(v.x); o.y = f2bf(v.y); o.z = f2bf(v.z); o.w = f2bf(v.w);
    *(ushort4*)&tile[r + p * 16][c4] = o;
    cp0 += v.x; cp1 += v.y; cp2 += v.z; cp3 += v.w;
  }
  csum[r][c4] = cp0; csum[r][c4 + 1] = cp1; csum[r][c4 + 2] = cp2; csum[r][c4 + 3] = cp3;
  __syncthreads();
  unsigned short* dst = inpT + (size_t)b * Dq * Sq + (size_t)dd * 64 * Sq + tt * 64;
#pragma unroll
  for (int p = 0; p < 4; ++p) {
    int d = (tid >> 4) + p * 16;
    int tq = (tid & 15) * 4;
    ushort4 o;
    o.x = tile[tq][d]; o.y = tile[tq + 1][d]; o.z = tile[tq + 2][d]; o.w = tile[tq + 3][d];
    *(ushort4*)(dst + (size_t)d * Sq + tq) = o;
  }
  if (tid < 64) {
    float s = 0.f;
#pragma unroll
    for (int rr = 0; rr < 16; ++rr) s += csum[rr][tid];
    partial[((size_t)b * 16 + tt) * Dq + dd * 64 + tid] = s;
  }
}

// ================= dispatch 2: gram_fac + casts =================
// idx<1024: gram tiles; 1024..1535: fac; 1536..2047: aspect cast (no deps);
// 2048..2559: w1/w2 cast into permuted+swizzled layout (no deps).
__global__ __launch_bounds__(256, 5) void gram_fac(
    const unsigned short* __restrict__ inpT, const float* __restrict__ partial,
    const float* __restrict__ aspect, const float* __restrict__ lenv,
    const float* __restrict__ w1, const float* __restrict__ w2,
    unsigned short* __restrict__ Gm, float* __restrict__ fac,
    unsigned short* __restrict__ asp_bf,
    unsigned short* __restrict__ w1b, unsigned short* __restrict__ w2b) {
  __shared__ unsigned short sA[2][32 * 64];
  __shared__ unsigned short sB[2][64 * 64];
  int idx = blockIdx.x;
  int tid = threadIdx.x;
  int lane = tid & 63, wave = tid >> 6;

  if (idx >= 2048) {  // ---- w cast family ----
    int blk = idx - 2048;
    const float* src = (blk < 256) ? w1 : w2;
    unsigned short* dst = (blk < 256) ? w1b : w2b;
    int li = ((blk & 255) * 256 + tid) * 4;
    int n = li >> 9, k = li & 511;
    float4 v = *(const float4*)(src + li);
    ushort4 o; o.x = f2bf(v.x); o.y = f2bf(v.y); o.z = f2bf(v.z); o.w = f2bf(v.w);
    int x = ((k >> 3) & 3) ^ ((n >> 1) & 3);
    int off = (k >> 5) * 16384 + n * 32 + x * 8 + (k & 7);
    *(ushort4*)(dst + off) = o;
    return;
  }
  if (idx >= 1536) {  // ---- aspect cast family ----
    int blk = idx - 1536;
    const float* s = aspect + (size_t)blk * 8192 + tid * 4;
    unsigned short* d = asp_bf + (size_t)blk * 8192 + tid * 4;
#pragma unroll
    for (int j = 0; j < 8; ++j) {
      float4 v = *(const float4*)(s + j * 1024);
      ushort4 o; o.x = f2bf(v.x); o.y = f2bf(v.y); o.z = f2bf(v.z); o.w = f2bf(v.w);
      *(ushort4*)(d + j * 1024) = o;
    }
    return;
  }
  if (idx >= 1024) {  // ---- fac family (16 partial stripes) ----
    float* cs = (float*)sA;
    int fblk = idx - 1024;
    int b = fblk >> 6;
    int s0 = (fblk & 63) * 16;
#pragma unroll
    for (int h = 0; h < 2; ++h) {
      int d = h * 256 + tid;
      float s = 0.f;
      const float* p = partial + (size_t)b * 16 * Dq + d;
#pragma unroll
      for (int t = 0; t < 16; ++t) s += p[t * Dq];
      cs[d] = s;
    }
    __syncthreads();
    int g = lane >> 4, lr = lane & 15;
    int row = s0 + wave * 4 + g;
    const float* a = aspect + ((size_t)b * Sq + row) * Dq + lr * 32;
    float sum = 0.f;
#pragma unroll
    for (int j = 0; j < 8; ++j) {
      float4 v = *(const float4*)(a + j * 4);
      const float* c = cs + lr * 32 + j * 4;
      sum += v.x * c[0] + v.y * c[1] + v.z * c[2] + v.w * c[3];
    }
#pragma unroll
    for (int off = 1; off < 16; off <<= 1) sum += __shfl_xor(sum, off, 64);
    if (lr == 0) {
      float len = lenv[b];
      float scale = sqrtf(len);
      float f = 0.f;
      if (row < (int)len) f = 1.f / (scale * (sum / scale + 1e-4f));
      fac[b * Sq + row] = f;
    }
    return;
  }

  // ---- gram family ----
  const int K = 1024;
  int b = idx & 7;
  int tile = idx >> 3;
  int bm = tile & 15, bn = tile >> 4;
  const unsigned short* Ab = inpT + (size_t)b * Dq * Sq + (size_t)bm * 32 * K;
  const unsigned short* Bb = inpT + (size_t)b * Dq * Sq + (size_t)bn * 64 * K;
  int lr = lane & 15, lq = lane >> 4;
  int x7 = lr & 7;
  int l3 = lane >> 3, l7 = lane & 7;

  const unsigned short* gA = Ab + (size_t)(wave * 8 + l3) * K + (l7 ^ l3) * 8;
  const unsigned short* gB = Bb + (size_t)(wave * 16 + l3) * K + (l7 ^ l3) * 8;
  int dbaseA = (wave * 64 + lane) * 8;
  int dbaseB0 = (wave * 128 + lane) * 8;
  int dbaseB1 = (wave * 128 + 64 + lane) * 8;

  f32x4 acc[2] = {};

  auto issue = [&](int buf, int k0) {
    load_lds16(gA + k0, &sA[buf][dbaseA]);
    load_lds16(gB + k0, &sB[buf][dbaseB0]);
    load_lds16(gB + (size_t)8 * K + k0, &sB[buf][dbaseB1]);
  };

  int wm = (wave & 1) * 16, wn = (wave >> 1) * 32;
  issue(0, 0);
#pragma unroll
  for (int it = 0; it < 16; ++it) {
    int cur = it & 1;
    if (it + 1 < 16) {
      issue(cur ^ 1, (it + 1) << 6);
      asm volatile("s_waitcnt vmcnt(3)" ::: "memory");
    } else {
      asm volatile("s_waitcnt vmcnt(0)" ::: "memory");
    }
    __builtin_amdgcn_s_barrier();
#pragma unroll
    for (int c = 0; c < 2; ++c) {
      int g = c * 4 + lq;
      bf16x8 a0 = *(const bf16x8*)&sA[cur][((wm + lr) * 8 + (g ^ x7)) * 8];
      bf16x8 b0 = *(const bf16x8*)&sB[cur][((wn + lr) * 8 + (g ^ x7)) * 8];
      bf16x8 b1 = *(const bf16x8*)&sB[cur][((wn + 16 + lr) * 8 + (g ^ x7)) * 8];
      acc[0] = __builtin_amdgcn_mfma_f32_16x16x32_bf16(a0, b0, acc[0], 0, 0, 0);
      acc[1] = __builtin_amdgcn_mfma_f32_16x16x32_bf16(a0, b1, acc[1], 0, 0, 0);
    }
    asm volatile("s_waitcnt lgkmcnt(0)" ::: "memory");
    __builtin_amdgcn_sched_barrier(0);
    __builtin_amdgcn_s_barrier();
  }

  // Epilogue: store C[r][c] as B[n=c][k=r] (Gram symmetric), chunk kc=bm,
  // with the bank-quad swizzle baked in; global copy = contiguous 4KB.
  unsigned short* sP = sA[0];
#pragma unroll
  for (int ni = 0; ni < 2; ++ni)
#pragma unroll
    for (int i = 0; i < 4; ++i) {
      int rl = wm + lq * 4 + i;
      int ccl = wn + ni * 16 + lr;
      int x = (rl >> 3) ^ ((ccl >> 1) & 3);
      sP[ccl * 32 + x * 8 + (rl & 7)] = f2bf(acc[ni][i]);
    }
  __syncthreads();
  unsigned short* Ob = Gm + (size_t)b * 512 * 512 + (size_t)bm * 16384 + (size_t)bn * 2048;
  *(bf16x8*)(Ob + tid * 8) = *(const bf16x8*)(sP + tid * 8);
}

// ================= dispatch 3: mega — 16-row blocks, 2 blocks/CU ============
// 512 blocks x 512 thr. 16 rows/block, 8 waves x 64-col slice. af[16] = 64
// VGPR (fits 128-VGPR cap -> A truly register-resident). LDS = 16KB swizzled
// ldsA + 2x32KB wbuf = 80KB exactly -> 2 blocks/CU (independent barrier
// domains hide DMA/barrier stalls). ssqW overlays wbuf after last GEMM.
#define MEGA_SMEM (16 * 512 * 2 + 2 * 16384 * 2)  // 81920 B

__global__ __launch_bounds__(512, 4) void mega_ffn(
    const unsigned short* __restrict__ aspb, const unsigned short* __restrict__ G,
    const unsigned short* __restrict__ w1b, const unsigned short* __restrict__ w2b,
    const float* __restrict__ b1, const float* __restrict__ b2,
    const float* __restrict__ inp, const float* __restrict__ aspect,
    const float* __restrict__ fac, const float* __restrict__ lenv,
    float* __restrict__ out) {
  extern __shared__ char smem[];
  unsigned short* ldsA = (unsigned short*)smem;                  // 16KB, XOR-swz
  unsigned short* wbuf = (unsigned short*)(smem + 16 * 512 * 2); // 2x32KB
  int tid = threadIdx.x;
  int lane = tid & 63, wave = tid >> 6;
  int lr = lane & 15, lq = lane >> 4;
  int xb = blockIdx.x;
  int bid = ((xb & 7) << 6) | (xb >> 3);  // batch -> XCD pin (512 blocks)
  int r0 = bid * 16;
  int b = bid >> 6;
  int c0 = wave * 64;

  bf16x8 af[16];
  f32x4 acc[4];
  float ffnv[4][4];

  int bx = (lq ^ ((lr >> 1) & 3)) * 8;
  int rdbase = (c0 + lr) * 32 + bx;

  // ldsA XOR swizzle: bank-quad of col xored with row&7 (bijective, pad-free)
  auto aoff = [&](int rr, int c) {
    int cq = c >> 3;
    return rr * 512 + ((cq ^ (rr & 7)) << 3) + (c & 7);
  };

  int soff = tid * 8;
  auto stage = [&](int buf, int kc, const unsigned short* Bsrc) {
    const unsigned short* src = Bsrc + kc * 16384;
    unsigned short* dstb = wbuf + buf * 16384;
#pragma unroll
    for (int i = 0; i < 4; ++i)
      load_lds16(src + i * 4096 + soff, dstb + i * 4096 + soff);
  };

  auto gemmPhase = [&](const unsigned short* Bsrc) {
#pragma unroll
    for (int t = 0; t < 4; ++t) acc[t] = (f32x4){0.f, 0.f, 0.f, 0.f};
    stage(0, 0, Bsrc);
#pragma unroll
    for (int kc = 0; kc < 16; ++kc) {
      int cur = kc & 1;
      if (kc < 15) {
        stage(cur ^ 1, kc + 1, Bsrc);
        asm volatile("s_waitcnt vmcnt(4)" ::: "memory");
      } else {
        asm volatile("s_waitcnt vmcnt(0)" ::: "memory");
      }
      __builtin_amdgcn_s_barrier();  // tile kc staged
      bf16x8 bfr[4];
#pragma unroll
      for (int t = 0; t < 4; ++t)
        bfr[t] = *(const bf16x8*)&wbuf[cur * 16384 + rdbase + t * 512];
#pragma unroll
      for (int t = 0; t < 4; ++t)
        acc[t] = __builtin_amdgcn_mfma_f32_16x16x32_bf16(af[kc], bfr[t], acc[t], 0, 0, 0);
      asm volatile("s_waitcnt lgkmcnt(0)" ::: "memory");
      __builtin_amdgcn_sched_barrier(0);
      __builtin_amdgcn_s_barrier();  // buf[cur] free
    }
  };

  // ================= phase 0 =================
#pragma unroll
  for (int j = 0; j < 16; ++j)
    af[j] = *(const bf16x8*)(aspb + (size_t)(r0 + lr) * 512 + j * 32 + lq * 8);
  gemmPhase(G + (size_t)b * 512 * 512);
  int len = (int)lenv[b];
  float facv[4];
#pragma unroll
  for (int i = 0; i < 4; ++i) facv[i] = fac[r0 + lq * 4 + i];
#pragma unroll
  for (int t = 0; t < 4; ++t)
#pragma unroll
    for (int i = 0; i < 4; ++i) {
      int rr = lq * 4 + i;
      int r = r0 + rr;
      size_t idx = (size_t)r * 512 + c0 + t * 16 + lr;
      float add = ((r & 1023) < len) ? (inp[idx] + aspect[idx]) : 0.f;
      float v = acc[t][i] * facv[i] + add;
      ffnv[t][i] = v;
      ldsA[aoff(rr, c0 + t * 16 + lr)] = f2bf(v);
    }
  __syncthreads();

  // ================= phase 1 =================
#pragma unroll
  for (int j = 0; j < 16; ++j)
    af[j] = *(const bf16x8*)&ldsA[aoff(lr, j * 32 + lq * 8)];
  __syncthreads();
  gemmPhase(w1b);
  float biasv[4];
#pragma unroll
  for (int t = 0; t < 4; ++t) biasv[t] = b1[c0 + t * 16 + lr];
#pragma unroll
  for (int t = 0; t < 4; ++t)
#pragma unroll
    for (int i = 0; i < 4; ++i) {
      int rr = lq * 4 + i;
      ldsA[aoff(rr, c0 + t * 16 + lr)] = f2bf(fmaxf(acc[t][i] + biasv[t], 0.f));
    }
  __syncthreads();

  // ================= phase 2 + norm =================
#pragma unroll
  for (int j = 0; j < 16; ++j)
    af[j] = *(const bf16x8*)&ldsA[aoff(lr, j * 32 + lq * 8)];
  __syncthreads();
  gemmPhase(w2b);
#pragma unroll
  for (int t = 0; t < 4; ++t) biasv[t] = b2[c0 + t * 16 + lr];
  float ssq[4] = {0.f, 0.f, 0.f, 0.f};
#pragma unroll
  for (int t = 0; t < 4; ++t)
#pragma unroll
    for (int i = 0; i < 4; ++i) {
      float v = 2.f * ffnv[t][i] + fmaxf(acc[t][i] + biasv[t], 0.f);
      ffnv[t][i] = v;
      ssq[i] += v * v;
    }
#pragma unroll
  for (int off = 1; off < 16; off <<= 1)
#pragma unroll
    for (int i = 0; i < 4; ++i) ssq[i] += __shfl_xor(ssq[i], off, 64);
  float* ssqW = (float*)wbuf;  // wbuf free after last gemmPhase barrier
  if (lr == 0)
#pragma unroll
    for (int i = 0; i < 4; ++i) ssqW[wave * 16 + lq * 4 + i] = ssq[i];
  __syncthreads();
  float rn[4];
#pragma unroll
  for (int i = 0; i < 4; ++i) {
    float s = 0.f;
#pragma unroll
    for (int w = 0; w < 8; ++w) s += ssqW[w * 16 + lq * 4 + i];
    rn[i] = 1.f / sqrtf(s);
  }
#pragma unroll
  for (int t = 0; t < 4; ++t)
#pragma unroll
    for (int i = 0; i < 4; ++i) {
      int r = r0 + lq * 4 + i;
      out[(size_t)r * 512 + c0 + t * 16 + lr] = ffnv[t][i] * rn[i];
    }
}

extern "C" void kernel_launch(void* const* d_in, const int* in_sizes, int n_in,
                              void* d_out, int out_size, void* d_ws, size_t ws_size,
                              hipStream_t stream) {
  const float* inp = (const float*)d_in[0];
  const float* inp_len = (const float*)d_in[1];
  const float* aspect = (const float*)d_in[2];
  const float* w1 = (const float*)d_in[3];
  const float* b1 = (const float*)d_in[4];
  const float* w2 = (const float*)d_in[5];
  const float* b2 = (const float*)d_in[6];
  float* out = (float*)d_out;

  char* W = (char*)d_ws;
  const size_t MB = 1ull << 20;
  unsigned short* asp_bf = (unsigned short*)(W + 0);        // 8 MB
  unsigned short* inpT   = (unsigned short*)(W + 8 * MB);   // 8 MB
  unsigned short* Gm     = (unsigned short*)(W + 16 * MB);  // 4 MB (permuted+swz)
  unsigned short* w1bf   = (unsigned short*)(W + 20 * MB);  // 512 KB (permuted+swz)
  unsigned short* w2bf   = (unsigned short*)(W + 20 * MB + 512 * 1024);
  float*          partial= (float*)(W + 21 * MB);           // 256 KB (16 stripes)
  float*          fac    = (float*)(W + 22 * MB);           // 32 KB

  // 1) transpose + colsum only (casts moved off the critical path)
  prep_t<<<1024, 256, 0, stream>>>(inp, inpT, partial);

  // 2) gram (1024) + fac (512) + aspect cast (512) + w cast (512)
  gram_fac<<<2560, 256, 0, stream>>>(inpT, partial, aspect, inp_len, w1, w2,
                                     Gm, fac, asp_bf, w1bf, w2bf);

  // 3) mega: 512 x 16-row blocks, 2 blocks/CU
  hipFuncSetAttribute((const void*)mega_ffn,
                      hipFuncAttributeMaxDynamicSharedMemorySize, MEGA_SMEM);
  mega_ffn<<<512, 512, MEGA_SMEM, stream>>>(
      asp_bf, Gm, w1bf, w2bf, b1, b2, inp, aspect, fac, inp_len, out);
}

// Round 6
// 139.601 us; speedup vs baseline: 1.0912x; 1.0912x over previous
//
#include <hip/hip_runtime.h>

#define Bq 8
#define Sq 1024
#define Dq 512

typedef __attribute__((ext_vector_type(8))) short bf16x8;
typedef __attribute__((ext_vector_type(4))) float f32x4;

__device__ __forceinline__ unsigned short f2bf(float f) {
  unsigned int u = __float_as_uint(f);
  return (unsigned short)((u + 0x7fffu + ((u >> 16) & 1u)) >> 16);
}

__device__ __forceinline__ void load_lds16(const unsigned short* g, unsigned short* l) {
  __builtin_amdgcn_global_load_lds(
      (const __attribute__((address_space(1))) unsigned int*)g,
      (__attribute__((address_space(3))) unsigned int*)l, 16, 0, 0);
}

// Permuted+swizzled B layout ("k-chunk-major"): element B[n][k] lives at
//   kc*16384 + n*32 + ((ksg ^ ((n>>1)&3))*8) + k7
// kc = k>>5, ksg = (k>>3)&3, k7 = k&7. Chunk = the 32KB LDS staging image.

// ================= dispatch 1: prep_t — inp transpose + colsum =============
__global__ __launch_bounds__(256) void prep_t(
    const float* __restrict__ inp,
    unsigned short* __restrict__ inpT, float* __restrict__ partial) {
  __shared__ unsigned short tile[64][66];
  __shared__ float csum[16][64];
  int idx = blockIdx.x;
  int tid = threadIdx.x;
  int b = idx & 7, tt = (idx >> 3) & 15, dd = idx >> 7;
  int r = tid >> 4, c4 = (tid & 15) * 4;
  const float* src = inp + ((size_t)b * Sq + tt * 64) * Dq + dd * 64;
  float cp0 = 0.f, cp1 = 0.f, cp2 = 0.f, cp3 = 0.f;
#pragma unroll
  for (int p = 0; p < 4; ++p) {
    float4 v = *(const float4*)(src + (size_t)(r + p * 16) * Dq + c4);
    ushort4 o; o.x = f2bf(v.x); o.y = f2bf(v.y); o.z = f2bf(v.z); o.w = f2bf(v.w);
    *(ushort4*)&tile[r + p * 16][c4] = o;
    cp0 += v.x; cp1 += v.y; cp2 += v.z; cp3 += v.w;
  }
  csum[r][c4] = cp0; csum[r][c4 + 1] = cp1; csum[r][c4 + 2] = cp2; csum[r][c4 + 3] = cp3;
  __syncthreads();
  unsigned short* dst = inpT + (size_t)b * Dq * Sq + (size_t)dd * 64 * Sq + tt * 64;
#pragma unroll
  for (int p = 0; p < 4; ++p) {
    int d = (tid >> 4) + p * 16;
    int tq = (tid & 15) * 4;
    ushort4 o;
    o.x = tile[tq][d]; o.y = tile[tq + 1][d]; o.z = tile[tq + 2][d]; o.w = tile[tq + 3][d];
    *(ushort4*)(dst + (size_t)d * Sq + tq) = o;
  }
  if (tid < 64) {
    float s = 0.f;
#pragma unroll
    for (int rr = 0; rr < 16; ++rr) s += csum[rr][tid];
    partial[((size_t)b * 16 + tt) * Dq + dd * 64 + tid] = s;
  }
}

// ================= dispatch 2: gram_fac + casts =================
__global__ __launch_bounds__(256, 5) void gram_fac(
    const unsigned short* __restrict__ inpT, const float* __restrict__ partial,
    const float* __restrict__ aspect, const float* __restrict__ lenv,
    const float* __restrict__ w1, const float* __restrict__ w2,
    unsigned short* __restrict__ Gm, float* __restrict__ fac,
    unsigned short* __restrict__ asp_bf,
    unsigned short* __restrict__ w1b, unsigned short* __restrict__ w2b) {
  __shared__ unsigned short sA[2][32 * 64];
  __shared__ unsigned short sB[2][64 * 64];
  int idx = blockIdx.x;
  int tid = threadIdx.x;
  int lane = tid & 63, wave = tid >> 6;

  if (idx >= 2048) {  // ---- w cast family ----
    int blk = idx - 2048;
    const float* src = (blk < 256) ? w1 : w2;
    unsigned short* dst = (blk < 256) ? w1b : w2b;
    int li = ((blk & 255) * 256 + tid) * 4;
    int n = li >> 9, k = li & 511;
    float4 v = *(const float4*)(src + li);
    ushort4 o; o.x = f2bf(v.x); o.y = f2bf(v.y); o.z = f2bf(v.z); o.w = f2bf(v.w);
    int x = ((k >> 3) & 3) ^ ((n >> 1) & 3);
    int off = (k >> 5) * 16384 + n * 32 + x * 8 + (k & 7);
    *(ushort4*)(dst + off) = o;
    return;
  }
  if (idx >= 1536) {  // ---- aspect cast family ----
    int blk = idx - 1536;
    const float* s = aspect + (size_t)blk * 8192 + tid * 4;
    unsigned short* d = asp_bf + (size_t)blk * 8192 + tid * 4;
#pragma unroll
    for (int j = 0; j < 8; ++j) {
      float4 v = *(const float4*)(s + j * 1024);
      ushort4 o; o.x = f2bf(v.x); o.y = f2bf(v.y); o.z = f2bf(v.z); o.w = f2bf(v.w);
      *(ushort4*)(d + j * 1024) = o;
    }
    return;
  }
  if (idx >= 1024) {  // ---- fac family ----
    float* cs = (float*)sA;
    int fblk = idx - 1024;
    int b = fblk >> 6;
    int s0 = (fblk & 63) * 16;
#pragma unroll
    for (int h = 0; h < 2; ++h) {
      int d = h * 256 + tid;
      float s = 0.f;
      const float* p = partial + (size_t)b * 16 * Dq + d;
#pragma unroll
      for (int t = 0; t < 16; ++t) s += p[t * Dq];
      cs[d] = s;
    }
    __syncthreads();
    int g = lane >> 4, lr = lane & 15;
    int row = s0 + wave * 4 + g;
    const float* a = aspect + ((size_t)b * Sq + row) * Dq + lr * 32;
    float sum = 0.f;
#pragma unroll
    for (int j = 0; j < 8; ++j) {
      float4 v = *(const float4*)(a + j * 4);
      const float* c = cs + lr * 32 + j * 4;
      sum += v.x * c[0] + v.y * c[1] + v.z * c[2] + v.w * c[3];
    }
#pragma unroll
    for (int off = 1; off < 16; off <<= 1) sum += __shfl_xor(sum, off, 64);
    if (lr == 0) {
      float len = lenv[b];
      float scale = sqrtf(len);
      float f = 0.f;
      if (row < (int)len) f = 1.f / (scale * (sum / scale + 1e-4f));
      fac[b * Sq + row] = f;
    }
    return;
  }

  // ---- gram family ----
  const int K = 1024;
  int b = idx & 7;
  int tile = idx >> 3;
  int bm = tile & 15, bn = tile >> 4;
  const unsigned short* Ab = inpT + (size_t)b * Dq * Sq + (size_t)bm * 32 * K;
  const unsigned short* Bb = inpT + (size_t)b * Dq * Sq + (size_t)bn * 64 * K;
  int lr = lane & 15, lq = lane >> 4;
  int x7 = lr & 7;
  int l3 = lane >> 3, l7 = lane & 7;

  const unsigned short* gA = Ab + (size_t)(wave * 8 + l3) * K + (l7 ^ l3) * 8;
  const unsigned short* gB = Bb + (size_t)(wave * 16 + l3) * K + (l7 ^ l3) * 8;
  int dbaseA = (wave * 64 + lane) * 8;
  int dbaseB0 = (wave * 128 + lane) * 8;
  int dbaseB1 = (wave * 128 + 64 + lane) * 8;

  f32x4 acc[2] = {};

  auto issue = [&](int buf, int k0) {
    load_lds16(gA + k0, &sA[buf][dbaseA]);
    load_lds16(gB + k0, &sB[buf][dbaseB0]);
    load_lds16(gB + (size_t)8 * K + k0, &sB[buf][dbaseB1]);
  };

  int wm = (wave & 1) * 16, wn = (wave >> 1) * 32;
  issue(0, 0);
#pragma unroll
  for (int it = 0; it < 16; ++it) {
    int cur = it & 1;
    if (it + 1 < 16) {
      issue(cur ^ 1, (it + 1) << 6);
      asm volatile("s_waitcnt vmcnt(3)" ::: "memory");
    } else {
      asm volatile("s_waitcnt vmcnt(0)" ::: "memory");
    }
    __builtin_amdgcn_s_barrier();
#pragma unroll
    for (int c = 0; c < 2; ++c) {
      int g = c * 4 + lq;
      bf16x8 a0 = *(const bf16x8*)&sA[cur][((wm + lr) * 8 + (g ^ x7)) * 8];
      bf16x8 b0 = *(const bf16x8*)&sB[cur][((wn + lr) * 8 + (g ^ x7)) * 8];
      bf16x8 b1 = *(const bf16x8*)&sB[cur][((wn + 16 + lr) * 8 + (g ^ x7)) * 8];
      acc[0] = __builtin_amdgcn_mfma_f32_16x16x32_bf16(a0, b0, acc[0], 0, 0, 0);
      acc[1] = __builtin_amdgcn_mfma_f32_16x16x32_bf16(a0, b1, acc[1], 0, 0, 0);
    }
    asm volatile("s_waitcnt lgkmcnt(0)" ::: "memory");
    __builtin_amdgcn_sched_barrier(0);
    __builtin_amdgcn_s_barrier();
  }

  unsigned short* sP = sA[0];
#pragma unroll
  for (int ni = 0; ni < 2; ++ni)
#pragma unroll
    for (int i = 0; i < 4; ++i) {
      int rl = wm + lq * 4 + i;
      int ccl = wn + ni * 16 + lr;
      int x = (rl >> 3) ^ ((ccl >> 1) & 3);
      sP[ccl * 32 + x * 8 + (rl & 7)] = f2bf(acc[ni][i]);
    }
  __syncthreads();
  unsigned short* Ob = Gm + (size_t)b * 512 * 512 + (size_t)bm * 16384 + (size_t)bn * 2048;
  *(bf16x8*)(Ob + tid * 8) = *(const bf16x8*)(sP + tid * 8);
}

// ================= dispatch 3: mega — A-in-LDS, no big register arrays ======
// 512 blocks x 512 thr, 16 rows/block, 8 waves x 64-col slice. A is read from
// swizzled ldsA per k-step (1 extra ds_read_b128) instead of af[16] registers
// -> ~90 VGPR, no spill, 4 waves/SIMD; LDS 80KB -> 2 real blocks/CU whose
// independent barrier domains hide each other's DMA waits.
#define MEGA_SMEM (16 * 512 * 2 + 2 * 16384 * 2)  // 16KB ldsA + 64KB wbuf

__global__ __launch_bounds__(512, 4) void mega_ffn(
    const unsigned short* __restrict__ aspb, const unsigned short* __restrict__ G,
    const unsigned short* __restrict__ w1b, const unsigned short* __restrict__ w2b,
    const float* __restrict__ b1, const float* __restrict__ b2,
    const float* __restrict__ inp, const float* __restrict__ aspect,
    const float* __restrict__ fac, const float* __restrict__ lenv,
    float* __restrict__ out) {
  extern __shared__ char smem[];
  unsigned short* ldsA = (unsigned short*)smem;                  // 16KB, XOR-swz
  unsigned short* wbuf = (unsigned short*)(smem + 16 * 512 * 2); // 2x32KB
  int tid = threadIdx.x;
  int lane = tid & 63, wave = tid >> 6;
  int lr = lane & 15, lq = lane >> 4;
  int xb = blockIdx.x;
  int bid = ((xb & 7) << 6) | (xb >> 3);  // batch -> XCD pin
  int r0 = bid * 16;
  int b = bid >> 6;
  int c0 = wave * 64;

  f32x4 acc[4];
  float ffnv[4][4];

  int bx = (lq ^ ((lr >> 1) & 3)) * 8;
  int rdbase = (c0 + lr) * 32 + bx;

  // ldsA swizzle: quad index of col XORed with row&7 (bijective, pad-free).
  auto aoff = [&](int rr, int c) {
    int cq = c >> 3;
    return rr * 512 + ((cq ^ (rr & 7)) << 3) + (c & 7);
  };

  int soff = tid * 8;
  auto stage = [&](int buf, int kc, const unsigned short* Bsrc) {
    const unsigned short* src = Bsrc + kc * 16384;
    unsigned short* dstb = wbuf + buf * 16384;
#pragma unroll
    for (int i = 0; i < 4; ++i)
      load_lds16(src + i * 4096 + soff, dstb + i * 4096 + soff);
  };

  auto gemmPhase = [&](const unsigned short* Bsrc) {
#pragma unroll
    for (int t = 0; t < 4; ++t) acc[t] = (f32x4){0.f, 0.f, 0.f, 0.f};
    stage(0, 0, Bsrc);
#pragma unroll
    for (int kc = 0; kc < 16; ++kc) {
      int cur = kc & 1;
      if (kc < 15) {
        stage(cur ^ 1, kc + 1, Bsrc);
        asm volatile("s_waitcnt vmcnt(4)" ::: "memory");
      } else {
        asm volatile("s_waitcnt vmcnt(0)" ::: "memory");
      }
      __builtin_amdgcn_s_barrier();  // tile kc staged
      bf16x8 afr = *(const bf16x8*)&ldsA[aoff(lr, kc * 32 + lq * 8)];
      bf16x8 bfr[4];
#pragma unroll
      for (int t = 0; t < 4; ++t)
        bfr[t] = *(const bf16x8*)&wbuf[cur * 16384 + rdbase + t * 512];
#pragma unroll
      for (int t = 0; t < 4; ++t)
        acc[t] = __builtin_amdgcn_mfma_f32_16x16x32_bf16(afr, bfr[t], acc[t], 0, 0, 0);
      asm volatile("s_waitcnt lgkmcnt(0)" ::: "memory");
      __builtin_amdgcn_sched_barrier(0);
      __builtin_amdgcn_s_barrier();  // buf[cur] free
    }
  };

  // stage aspb rows r0..r0+15 into ldsA: linear LDS dest (DMA requirement),
  // inverse-swizzled GLOBAL source (m173 pattern) so reads use aoff().
#pragma unroll
  for (int h = 0; h < 2; ++h) {
    int s = h * 512 + tid;       // quad-slot 0..1023
    int rr = s >> 6;             // row
    int sq = s & 63;             // stored quad within row
    int cq = sq ^ (rr & 7);      // logical col quad (XOR is an involution)
    load_lds16(aspb + (size_t)(r0 + rr) * 512 + cq * 8, ldsA + s * 8);
  }
  // (these 2 loads complete before the first vmcnt(4) inside gemmPhase:
  //  FIFO order 2 A-loads + 4 stage0 + 4 stage1 -> vmcnt(4) drains A+stage0)

  // ================= phase 0 =================
  gemmPhase(G + (size_t)b * 512 * 512);
  int len = (int)lenv[b];
  float facv[4];
#pragma unroll
  for (int i = 0; i < 4; ++i) facv[i] = fac[r0 + lq * 4 + i];
#pragma unroll
  for (int t = 0; t < 4; ++t)
#pragma unroll
    for (int i = 0; i < 4; ++i) {
      int rr = lq * 4 + i;
      int r = r0 + rr;
      size_t idx = (size_t)r * 512 + c0 + t * 16 + lr;
      float add = ((r & 1023) < len) ? (inp[idx] + aspect[idx]) : 0.f;
      float v = acc[t][i] * facv[i] + add;
      ffnv[t][i] = v;
      ldsA[aoff(rr, c0 + t * 16 + lr)] = f2bf(v);
    }
  __syncthreads();

  // ================= phase 1 =================
  gemmPhase(w1b);
  float biasv[4];
#pragma unroll
  for (int t = 0; t < 4; ++t) biasv[t] = b1[c0 + t * 16 + lr];
#pragma unroll
  for (int t = 0; t < 4; ++t)
#pragma unroll
    for (int i = 0; i < 4; ++i) {
      int rr = lq * 4 + i;
      ldsA[aoff(rr, c0 + t * 16 + lr)] = f2bf(fmaxf(acc[t][i] + biasv[t], 0.f));
    }
  __syncthreads();

  // ================= phase 2 + norm =================
  gemmPhase(w2b);
#pragma unroll
  for (int t = 0; t < 4; ++t) biasv[t] = b2[c0 + t * 16 + lr];
  float ssq[4] = {0.f, 0.f, 0.f, 0.f};
#pragma unroll
  for (int t = 0; t < 4; ++t)
#pragma unroll
    for (int i = 0; i < 4; ++i) {
      float v = 2.f * ffnv[t][i] + fmaxf(acc[t][i] + biasv[t], 0.f);
      ffnv[t][i] = v;
      ssq[i] += v * v;
    }
#pragma unroll
  for (int off = 1; off < 16; off <<= 1)
#pragma unroll
    for (int i = 0; i < 4; ++i) ssq[i] += __shfl_xor(ssq[i], off, 64);
  float* ssqW = (float*)wbuf;  // wbuf free after last gemmPhase
  if (lr == 0)
#pragma unroll
    for (int i = 0; i < 4; ++i) ssqW[wave * 16 + lq * 4 + i] = ssq[i];
  __syncthreads();
  float rn[4];
#pragma unroll
  for (int i = 0; i < 4; ++i) {
    float s = 0.f;
#pragma unroll
    for (int w = 0; w < 8; ++w) s += ssqW[w * 16 + lq * 4 + i];
    rn[i] = 1.f / sqrtf(s);
  }
#pragma unroll
  for (int t = 0; t < 4; ++t)
#pragma unroll
    for (int i = 0; i < 4; ++i) {
      int r = r0 + lq * 4 + i;
      out[(size_t)r * 512 + c0 + t * 16 + lr] = ffnv[t][i] * rn[i];
    }
}

extern "C" void kernel_launch(void* const* d_in, const int* in_sizes, int n_in,
                              void* d_out, int out_size, void* d_ws, size_t ws_size,
                              hipStream_t stream) {
  const float* inp = (const float*)d_in[0];
  const float* inp_len = (const float*)d_in[1];
  const float* aspect = (const float*)d_in[2];
  const float* w1 = (const float*)d_in[3];
  const float* b1 = (const float*)d_in[4];
  const float* w2 = (const float*)d_in[5];
  const float* b2 = (const float*)d_in[6];
  float* out = (float*)d_out;

  char* W = (char*)d_ws;
  const size_t MB = 1ull << 20;
  unsigned short* asp_bf = (unsigned short*)(W + 0);        // 8 MB
  unsigned short* inpT   = (unsigned short*)(W + 8 * MB);   // 8 MB
  unsigned short* Gm     = (unsigned short*)(W + 16 * MB);  // 4 MB (permuted+swz)
  unsigned short* w1bf   = (unsigned short*)(W + 20 * MB);  // 512 KB (permuted+swz)
  unsigned short* w2bf   = (unsigned short*)(W + 20 * MB + 512 * 1024);
  float*          partial= (float*)(W + 21 * MB);           // 256 KB
  float*          fac    = (float*)(W + 22 * MB);           // 32 KB

  prep_t<<<1024, 256, 0, stream>>>(inp, inpT, partial);

  gram_fac<<<2560, 256, 0, stream>>>(inpT, partial, aspect, inp_len, w1, w2,
                                     Gm, fac, asp_bf, w1bf, w2bf);

  hipFuncSetAttribute((const void*)mega_ffn,
                      hipFuncAttributeMaxDynamicSharedMemorySize, MEGA_SMEM);
  mega_ffn<<<512, 512, MEGA_SMEM, stream>>>(
      asp_bf, Gm, w1bf, w2bf, b1, b2, inp, aspect, fac, inp_len, out);
}

// Round 7
// 130.319 us; speedup vs baseline: 1.1689x; 1.0712x over previous
//
#include <hip/hip_runtime.h>

#define Bq 8
#define Sq 1024
#define Dq 512

typedef __attribute__((ext_vector_type(8))) short bf16x8;
typedef __attribute__((ext_vector_type(4))) float f32x4;

__device__ __forceinline__ unsigned short f2bf(float f) {
  unsigned int u = __float_as_uint(f);
  return (unsigned short)((u + 0x7fffu + ((u >> 16) & 1u)) >> 16);
}

__device__ __forceinline__ void load_lds16(const unsigned short* g, unsigned short* l) {
  __builtin_amdgcn_global_load_lds(
      (const __attribute__((address_space(1))) unsigned int*)g,
      (__attribute__((address_space(3))) unsigned int*)l, 16, 0, 0);
}

// Permuted+swizzled B layout ("k-chunk-major"): element B[n][k] lives at
//   kc*16384 + n*32 + ((ksg ^ ((n>>1)&3))*8) + k7
// kc = k>>5, ksg = (k>>3)&3, k7 = k&7. A wave's 64-col k-chunk slice is one
// contiguous 4KB span -> perfectly coalesced DIRECT global reads (no LDS hop).

// ================= dispatch 1: prep_t — inp transpose + colsum =============
__global__ __launch_bounds__(256) void prep_t(
    const float* __restrict__ inp,
    unsigned short* __restrict__ inpT, float* __restrict__ partial) {
  __shared__ unsigned short tile[64][66];
  __shared__ float csum[16][64];
  int idx = blockIdx.x;
  int tid = threadIdx.x;
  int b = idx & 7, tt = (idx >> 3) & 15, dd = idx >> 7;
  int r = tid >> 4, c4 = (tid & 15) * 4;
  const float* src = inp + ((size_t)b * Sq + tt * 64) * Dq + dd * 64;
  float cp0 = 0.f, cp1 = 0.f, cp2 = 0.f, cp3 = 0.f;
#pragma unroll
  for (int p = 0; p < 4; ++p) {
    float4 v = *(const float4*)(src + (size_t)(r + p * 16) * Dq + c4);
    ushort4 o; o.x = f2bf(v.x); o.y = f2bf(v.y); o.z = f2bf(v.z); o.w = f2bf(v.w);
    *(ushort4*)&tile[r + p * 16][c4] = o;
    cp0 += v.x; cp1 += v.y; cp2 += v.z; cp3 += v.w;
  }
  csum[r][c4] = cp0; csum[r][c4 + 1] = cp1; csum[r][c4 + 2] = cp2; csum[r][c4 + 3] = cp3;
  __syncthreads();
  unsigned short* dst = inpT + (size_t)b * Dq * Sq + (size_t)dd * 64 * Sq + tt * 64;
#pragma unroll
  for (int p = 0; p < 4; ++p) {
    int d = (tid >> 4) + p * 16;
    int tq = (tid & 15) * 4;
    ushort4 o;
    o.x = tile[tq][d]; o.y = tile[tq + 1][d]; o.z = tile[tq + 2][d]; o.w = tile[tq + 3][d];
    *(ushort4*)(dst + (size_t)d * Sq + tq) = o;
  }
  if (tid < 64) {
    float s = 0.f;
#pragma unroll
    for (int rr = 0; rr < 16; ++rr) s += csum[rr][tid];
    partial[((size_t)b * 16 + tt) * Dq + dd * 64 + tid] = s;
  }
}

// ================= dispatch 2: gram_fac + casts (unchanged) =================
__global__ __launch_bounds__(256, 5) void gram_fac(
    const unsigned short* __restrict__ inpT, const float* __restrict__ partial,
    const float* __restrict__ aspect, const float* __restrict__ lenv,
    const float* __restrict__ w1, const float* __restrict__ w2,
    unsigned short* __restrict__ Gm, float* __restrict__ fac,
    unsigned short* __restrict__ asp_bf,
    unsigned short* __restrict__ w1b, unsigned short* __restrict__ w2b) {
  __shared__ unsigned short sA[2][32 * 64];
  __shared__ unsigned short sB[2][64 * 64];
  int idx = blockIdx.x;
  int tid = threadIdx.x;
  int lane = tid & 63, wave = tid >> 6;

  if (idx >= 2048) {  // ---- w cast family ----
    int blk = idx - 2048;
    const float* src = (blk < 256) ? w1 : w2;
    unsigned short* dst = (blk < 256) ? w1b : w2b;
    int li = ((blk & 255) * 256 + tid) * 4;
    int n = li >> 9, k = li & 511;
    float4 v = *(const float4*)(src + li);
    ushort4 o; o.x = f2bf(v.x); o.y = f2bf(v.y); o.z = f2bf(v.z); o.w = f2bf(v.w);
    int x = ((k >> 3) & 3) ^ ((n >> 1) & 3);
    int off = (k >> 5) * 16384 + n * 32 + x * 8 + (k & 7);
    *(ushort4*)(dst + off) = o;
    return;
  }
  if (idx >= 1536) {  // ---- aspect cast family ----
    int blk = idx - 1536;
    const float* s = aspect + (size_t)blk * 8192 + tid * 4;
    unsigned short* d = asp_bf + (size_t)blk * 8192 + tid * 4;
#pragma unroll
    for (int j = 0; j < 8; ++j) {
      float4 v = *(const float4*)(s + j * 1024);
      ushort4 o; o.x = f2bf(v.x); o.y = f2bf(v.y); o.z = f2bf(v.z); o.w = f2bf(v.w);
      *(ushort4*)(d + j * 1024) = o;
    }
    return;
  }
  if (idx >= 1024) {  // ---- fac family ----
    float* cs = (float*)sA;
    int fblk = idx - 1024;
    int b = fblk >> 6;
    int s0 = (fblk & 63) * 16;
#pragma unroll
    for (int h = 0; h < 2; ++h) {
      int d = h * 256 + tid;
      float s = 0.f;
      const float* p = partial + (size_t)b * 16 * Dq + d;
#pragma unroll
      for (int t = 0; t < 16; ++t) s += p[t * Dq];
      cs[d] = s;
    }
    __syncthreads();
    int g = lane >> 4, lr = lane & 15;
    int row = s0 + wave * 4 + g;
    const float* a = aspect + ((size_t)b * Sq + row) * Dq + lr * 32;
    float sum = 0.f;
#pragma unroll
    for (int j = 0; j < 8; ++j) {
      float4 v = *(const float4*)(a + j * 4);
      const float* c = cs + lr * 32 + j * 4;
      sum += v.x * c[0] + v.y * c[1] + v.z * c[2] + v.w * c[3];
    }
#pragma unroll
    for (int off = 1; off < 16; off <<= 1) sum += __shfl_xor(sum, off, 64);
    if (lr == 0) {
      float len = lenv[b];
      float scale = sqrtf(len);
      float f = 0.f;
      if (row < (int)len) f = 1.f / (scale * (sum / scale + 1e-4f));
      fac[b * Sq + row] = f;
    }
    return;
  }

  // ---- gram family ----
  const int K = 1024;
  int b = idx & 7;
  int tile = idx >> 3;
  int bm = tile & 15, bn = tile >> 4;
  const unsigned short* Ab = inpT + (size_t)b * Dq * Sq + (size_t)bm * 32 * K;
  const unsigned short* Bb = inpT + (size_t)b * Dq * Sq + (size_t)bn * 64 * K;
  int lr = lane & 15, lq = lane >> 4;
  int x7 = lr & 7;
  int l3 = lane >> 3, l7 = lane & 7;

  const unsigned short* gA = Ab + (size_t)(wave * 8 + l3) * K + (l7 ^ l3) * 8;
  const unsigned short* gB = Bb + (size_t)(wave * 16 + l3) * K + (l7 ^ l3) * 8;
  int dbaseA = (wave * 64 + lane) * 8;
  int dbaseB0 = (wave * 128 + lane) * 8;
  int dbaseB1 = (wave * 128 + 64 + lane) * 8;

  f32x4 acc[2] = {};

  auto issue = [&](int buf, int k0) {
    load_lds16(gA + k0, &sA[buf][dbaseA]);
    load_lds16(gB + k0, &sB[buf][dbaseB0]);
    load_lds16(gB + (size_t)8 * K + k0, &sB[buf][dbaseB1]);
  };

  int wm = (wave & 1) * 16, wn = (wave >> 1) * 32;
  issue(0, 0);
#pragma unroll
  for (int it = 0; it < 16; ++it) {
    int cur = it & 1;
    if (it + 1 < 16) {
      issue(cur ^ 1, (it + 1) << 6);
      asm volatile("s_waitcnt vmcnt(3)" ::: "memory");
    } else {
      asm volatile("s_waitcnt vmcnt(0)" ::: "memory");
    }
    __builtin_amdgcn_s_barrier();
#pragma unroll
    for (int c = 0; c < 2; ++c) {
      int g = c * 4 + lq;
      bf16x8 a0 = *(const bf16x8*)&sA[cur][((wm + lr) * 8 + (g ^ x7)) * 8];
      bf16x8 b0 = *(const bf16x8*)&sB[cur][((wn + lr) * 8 + (g ^ x7)) * 8];
      bf16x8 b1 = *(const bf16x8*)&sB[cur][((wn + 16 + lr) * 8 + (g ^ x7)) * 8];
      acc[0] = __builtin_amdgcn_mfma_f32_16x16x32_bf16(a0, b0, acc[0], 0, 0, 0);
      acc[1] = __builtin_amdgcn_mfma_f32_16x16x32_bf16(a0, b1, acc[1], 0, 0, 0);
    }
    asm volatile("s_waitcnt lgkmcnt(0)" ::: "memory");
    __builtin_amdgcn_sched_barrier(0);
    __builtin_amdgcn_s_barrier();
  }

  unsigned short* sP = sA[0];
#pragma unroll
  for (int ni = 0; ni < 2; ++ni)
#pragma unroll
    for (int i = 0; i < 4; ++i) {
      int rl = wm + lq * 4 + i;
      int ccl = wn + ni * 16 + lr;
      int x = (rl >> 3) ^ ((ccl >> 1) & 3);
      sP[ccl * 32 + x * 8 + (rl & 7)] = f2bf(acc[ni][i]);
    }
  __syncthreads();
  unsigned short* Ob = Gm + (size_t)b * 512 * 512 + (size_t)bm * 16384 + (size_t)bn * 2048;
  *(bf16x8*)(Ob + tid * 8) = *(const bf16x8*)(sP + tid * 8);
}

// ================= dispatch 3: mega — direct-B, zero K-loop barriers ========
// 256 blocks x 512 thr, M=32 rows/block (1 block/CU, batch->XCD pinned).
// 8 waves x exclusive 64-col slice. B read DIRECTLY from the k-chunk-major
// global layout (contiguous 4KB/wave/chunk) into a 3-slot register pipeline —
// no wbuf, no staging DMA, no barriers inside the K-loop. A (32 rows) lives in
// swizzled ldsA. Waves free-run; latency hidden by depth-2.5 prefetch + TLP.
__global__ __launch_bounds__(512, 2) void mega_ffn(
    const unsigned short* __restrict__ aspb, const unsigned short* __restrict__ G,
    const unsigned short* __restrict__ w1b, const unsigned short* __restrict__ w2b,
    const float* __restrict__ b1, const float* __restrict__ b2,
    const float* __restrict__ inp, const float* __restrict__ aspect,
    const float* __restrict__ fac, const float* __restrict__ lenv,
    float* __restrict__ out) {
  __shared__ unsigned short ldsA[32 * 512];  // 32KB, XOR-swizzled
  __shared__ float ssqW[8 * 32];
  int tid = threadIdx.x;
  int lane = tid & 63, wave = tid >> 6;
  int lr = lane & 15, lq = lane >> 4;
  int batch = blockIdx.x & 7;   // XCD pin: all 32 blocks of batch b on XCD b
  int pos = blockIdx.x >> 3;    // 0..31
  int r0 = batch * 1024 + pos * 32;
  int c0 = wave * 64;

  f32x4 acc[2][4];
  float ffnv[2][4][4];

  // ldsA swizzle: col-quad XORed with row&7 (bijective, pad-free)
  auto aoff = [&](int rr, int c) {
    int cq = c >> 3;
    return rr * 512 + ((cq ^ (rr & 7)) << 3) + (c & 7);
  };
  // direct global B-frag address (k-chunk-major layout, ksg = lq)
  auto baddr = [&](const unsigned short* Bp, int kc, int cc) {
    return Bp + kc * 16384 + cc * 32 + ((lq ^ ((cc >> 1) & 3)) << 3);
  };

  // Barrier-free K-loop: 3-slot B prefetch (regs), 2-slot A prefetch (LDS).
  // All indices compile-time via full unroll (rule #20). Compiler inserts
  // counted vmcnt/lgkmcnt — no barrier ever forces a drain.
  auto gemmPhase = [&](const unsigned short* Bp) {
    bf16x8 bq[3][4];
    bf16x8 aq[2][2];
#pragma unroll
    for (int m = 0; m < 2; ++m)
#pragma unroll
      for (int t = 0; t < 4; ++t) acc[m][t] = (f32x4){0.f, 0.f, 0.f, 0.f};
#pragma unroll
    for (int t = 0; t < 4; ++t) {
      bq[0][t] = *(const bf16x8*)baddr(Bp, 0, c0 + t * 16 + lr);
      bq[1][t] = *(const bf16x8*)baddr(Bp, 1, c0 + t * 16 + lr);
    }
#pragma unroll
    for (int m = 0; m < 2; ++m)
      aq[0][m] = *(const bf16x8*)&ldsA[aoff(m * 16 + lr, lq * 8)];
#pragma unroll
    for (int kc = 0; kc < 16; ++kc) {
      if (kc + 2 < 16) {
#pragma unroll
        for (int t = 0; t < 4; ++t)
          bq[(kc + 2) % 3][t] = *(const bf16x8*)baddr(Bp, kc + 2, c0 + t * 16 + lr);
      }
      if (kc + 1 < 16) {
#pragma unroll
        for (int m = 0; m < 2; ++m)
          aq[(kc + 1) & 1][m] =
              *(const bf16x8*)&ldsA[aoff(m * 16 + lr, (kc + 1) * 32 + lq * 8)];
      }
      __builtin_amdgcn_s_setprio(1);
#pragma unroll
      for (int t = 0; t < 4; ++t) {
        acc[0][t] = __builtin_amdgcn_mfma_f32_16x16x32_bf16(aq[kc & 1][0], bq[kc % 3][t],
                                                            acc[0][t], 0, 0, 0);
        acc[1][t] = __builtin_amdgcn_mfma_f32_16x16x32_bf16(aq[kc & 1][1], bq[kc % 3][t],
                                                            acc[1][t], 0, 0, 0);
      }
      __builtin_amdgcn_s_setprio(0);
    }
  };

  // one-time: stage aspect rows r0..r0+31 into ldsA (linear LDS dest,
  // inverse-swizzled global source — m173 pattern)
#pragma unroll
  for (int h = 0; h < 8; ++h) {
    int s = h * 512 + tid;     // 8B-slot 0..4095
    int rr = s >> 6, sq = s & 63;
    int cq = sq ^ (rr & 7);    // XOR is an involution
    load_lds16(aspb + (size_t)(r0 + rr) * 512 + cq * 8, ldsA + s * 8);
  }
  asm volatile("s_waitcnt vmcnt(0)" ::: "memory");
  __syncthreads();

  // ================= phase 0: weighted + residual =================
  gemmPhase(G + (size_t)batch * 512 * 512);
  int len = (int)lenv[batch];
  float facv[2][4];
#pragma unroll
  for (int m = 0; m < 2; ++m)
#pragma unroll
    for (int i = 0; i < 4; ++i) facv[m][i] = fac[r0 + m * 16 + lq * 4 + i];
  __syncthreads();  // all waves done READING ldsA before overwrite
#pragma unroll
  for (int m = 0; m < 2; ++m)
#pragma unroll
    for (int t = 0; t < 4; ++t)
#pragma unroll
      for (int i = 0; i < 4; ++i) {
        int rr = m * 16 + lq * 4 + i;
        int gr = r0 + rr;
        size_t idx = (size_t)gr * 512 + c0 + t * 16 + lr;
        float add = ((gr & 1023) < len) ? (inp[idx] + aspect[idx]) : 0.f;
        float v = acc[m][t][i] * facv[m][i] + add;
        ffnv[m][t][i] = v;
        ldsA[aoff(rr, c0 + t * 16 + lr)] = f2bf(v);
      }
  __syncthreads();

  // ================= phase 1: relu(ffn_inp @ w1^T + b1) =================
  gemmPhase(w1b);
  float biasv[4];
#pragma unroll
  for (int t = 0; t < 4; ++t) biasv[t] = b1[c0 + t * 16 + lr];
  __syncthreads();
#pragma unroll
  for (int m = 0; m < 2; ++m)
#pragma unroll
    for (int t = 0; t < 4; ++t)
#pragma unroll
      for (int i = 0; i < 4; ++i) {
        int rr = m * 16 + lq * 4 + i;
        ldsA[aoff(rr, c0 + t * 16 + lr)] = f2bf(fmaxf(acc[m][t][i] + biasv[t], 0.f));
      }
  __syncthreads();

  // ================= phase 2 + norm =================
  gemmPhase(w2b);
#pragma unroll
  for (int t = 0; t < 4; ++t) biasv[t] = b2[c0 + t * 16 + lr];
  float ssq[2][4] = {{0.f, 0.f, 0.f, 0.f}, {0.f, 0.f, 0.f, 0.f}};
#pragma unroll
  for (int m = 0; m < 2; ++m)
#pragma unroll
    for (int t = 0; t < 4; ++t)
#pragma unroll
      for (int i = 0; i < 4; ++i) {
        float v = 2.f * ffnv[m][t][i] + fmaxf(acc[m][t][i] + biasv[t], 0.f);
        ffnv[m][t][i] = v;
        ssq[m][i] += v * v;
      }
#pragma unroll
  for (int off = 1; off < 16; off <<= 1)
#pragma unroll
    for (int m = 0; m < 2; ++m)
#pragma unroll
      for (int i = 0; i < 4; ++i) ssq[m][i] += __shfl_xor(ssq[m][i], off, 64);
  if (lr == 0)
#pragma unroll
    for (int m = 0; m < 2; ++m)
#pragma unroll
      for (int i = 0; i < 4; ++i) ssqW[wave * 32 + m * 16 + lq * 4 + i] = ssq[m][i];
  __syncthreads();
  float rn[2][4];
#pragma unroll
  for (int m = 0; m < 2; ++m)
#pragma unroll
    for (int i = 0; i < 4; ++i) {
      float s = 0.f;
#pragma unroll
      for (int w = 0; w < 8; ++w) s += ssqW[w * 32 + m * 16 + lq * 4 + i];
      rn[m][i] = 1.f / sqrtf(s);
    }
#pragma unroll
  for (int m = 0; m < 2; ++m)
#pragma unroll
    for (int t = 0; t < 4; ++t)
#pragma unroll
      for (int i = 0; i < 4; ++i) {
        int gr = r0 + m * 16 + lq * 4 + i;
        out[(size_t)gr * 512 + c0 + t * 16 + lr] = ffnv[m][t][i] * rn[m][i];
      }
}

extern "C" void kernel_launch(void* const* d_in, const int* in_sizes, int n_in,
                              void* d_out, int out_size, void* d_ws, size_t ws_size,
                              hipStream_t stream) {
  const float* inp = (const float*)d_in[0];
  const float* inp_len = (const float*)d_in[1];
  const float* aspect = (const float*)d_in[2];
  const float* w1 = (const float*)d_in[3];
  const float* b1 = (const float*)d_in[4];
  const float* w2 = (const float*)d_in[5];
  const float* b2 = (const float*)d_in[6];
  float* out = (float*)d_out;

  char* W = (char*)d_ws;
  const size_t MB = 1ull << 20;
  unsigned short* asp_bf = (unsigned short*)(W + 0);        // 8 MB
  unsigned short* inpT   = (unsigned short*)(W + 8 * MB);   // 8 MB
  unsigned short* Gm     = (unsigned short*)(W + 16 * MB);  // 4 MB (permuted+swz)
  unsigned short* w1bf   = (unsigned short*)(W + 20 * MB);  // 512 KB (permuted+swz)
  unsigned short* w2bf   = (unsigned short*)(W + 20 * MB + 512 * 1024);
  float*          partial= (float*)(W + 21 * MB);           // 256 KB
  float*          fac    = (float*)(W + 22 * MB);           // 32 KB

  prep_t<<<1024, 256, 0, stream>>>(inp, inpT, partial);

  gram_fac<<<2560, 256, 0, stream>>>(inpT, partial, aspect, inp_len, w1, w2,
                                     Gm, fac, asp_bf, w1bf, w2bf);

  // 256 x 32-row blocks, direct-B barrier-free K-loops, static 33KB LDS
  mega_ffn<<<256, 512, 0, stream>>>(
      asp_bf, Gm, w1bf, w2bf, b1, b2, inp, aspect, fac, inp_len, out);
}